// Round 4
// baseline (1026.403 us; speedup 1.0000x reference)
//
#include <hip/hip_runtime.h>
#include <hip/hip_fp16.h>

#define D 146
#define DP 160      // padded W leading dim in floats (40 float4 per row)
#define AS 152      // padded fp16 activation row (19 uint4 per row)
#define HWS 80      // hW16 gather-payload row stride in half2 (320B, 5 aligned lines)
#define NG 100
#define BN_EPS 1e-5f

// ---------------- pad weights into [5][146][160] fp32 ----------------
__global__ void padw_k(const float* __restrict__ Wemb, const float* __restrict__ Ws,
                       float* __restrict__ Wp)
{
    int idx = blockIdx.x * 256 + threadIdx.x;
    const int per = D * DP;
    if (idx >= 5 * per) return;
    int m = idx / per, rem = idx % per;
    int k = rem / DP, c = rem % DP;
    const float* Wsrc = (m == 0) ? Wemb : (Ws + (size_t)(m - 1) * D * D);
    Wp[idx] = (c < D) ? Wsrc[k * D + c] : 0.0f;
}

// ---------------- nodes fp32 [N][146] -> fp16 [N][152] ----------------
__global__ void cvtnodes_k(const float* __restrict__ nodes, __half2* __restrict__ out2, int N)
{
    int idx = blockIdx.x * 256 + threadIdx.x;
    if (idx >= N * (AS / 2)) return;
    int r = idx / (AS / 2), j = idx % (AS / 2);
    int c = 2 * j;
    float v0 = (c < D) ? nodes[(size_t)r * D + c] : 0.0f;
    float v1 = (c + 1 < D) ? nodes[(size_t)r * D + c + 1] : 0.0f;
    out2[idx] = __floats2half2_rn(v0, v1);
}

// ---------------- degree histograms ----------------
__global__ void deg_k(const int* __restrict__ src, const int* __restrict__ dst,
                      int* __restrict__ co, int* __restrict__ ci, int E)
{
    int e = blockIdx.x * 256 + threadIdx.x;
    if (e >= E) return;
    atomicAdd(&co[src[e]], 1);
    atomicAdd(&ci[dst[e]], 1);
}

__global__ void rsq_k(const int* __restrict__ co, const int* __restrict__ ci,
                      float* __restrict__ ns, float* __restrict__ nd, int N)
{
    int i = blockIdx.x * 256 + threadIdx.x;
    if (i >= N) return;
    ns[i] = rsqrtf(fmaxf((float)co[i], 1.0f));
    nd[i] = rsqrtf(fmaxf((float)ci[i], 1.0f));
}

// ---------------- parallel exclusive scan (3 phases) ----------------
__global__ __launch_bounds__(256) void pscan1_k(const int* __restrict__ cnt,
                                                int* __restrict__ bsum, int N)
{
    __shared__ int lds[256];
    int t = blockIdx.x * 256 + threadIdx.x;
    lds[threadIdx.x] = (t < N) ? cnt[t] : 0;
    __syncthreads();
    for (int s = 128; s > 0; s >>= 1) {
        if (threadIdx.x < s) lds[threadIdx.x] += lds[threadIdx.x + s];
        __syncthreads();
    }
    if (threadIdx.x == 0) bsum[blockIdx.x] = lds[0];
}

__global__ __launch_bounds__(256) void pscan2_k(const int* __restrict__ bsum,
                                                int* __restrict__ boff, int nb)
{
    __shared__ int lds[256];
    int t = threadIdx.x;
    int v = (t < nb) ? bsum[t] : 0;
    lds[t] = v;
    __syncthreads();
    for (int off = 1; off < 256; off <<= 1) {
        int u = (t >= off) ? lds[t - off] : 0;
        __syncthreads();
        lds[t] += u;
        __syncthreads();
    }
    boff[t] = lds[t] - v;
}

__global__ __launch_bounds__(256) void pscan3_k(const int* __restrict__ cnt,
                                                const int* __restrict__ boff,
                                                int* __restrict__ rowptr,
                                                int* __restrict__ cursor, int N, int E)
{
    __shared__ int lds[256];
    int t = blockIdx.x * 256 + threadIdx.x;
    int v = (t < N) ? cnt[t] : 0;
    lds[threadIdx.x] = v;
    __syncthreads();
    for (int off = 1; off < 256; off <<= 1) {
        int u = (threadIdx.x >= off) ? lds[threadIdx.x - off] : 0;
        __syncthreads();
        lds[threadIdx.x] += u;
        __syncthreads();
    }
    if (t < N) {
        int r = boff[blockIdx.x] + lds[threadIdx.x] - v;
        rowptr[t] = r;
        cursor[t] = r;
    }
    if (t == 0) rowptr[N] = E;
}

// ---------------- CSR fill ----------------
__global__ void csrfill_k(const int* __restrict__ src, const int* __restrict__ dst,
                          int* __restrict__ cursor, int* __restrict__ esrc, int E)
{
    int e = blockIdx.x * 256 + threadIdx.x;
    if (e >= E) return;
    int pos = atomicAdd(&cursor[dst[e]], 1);
    esrc[pos] = src[e];
}

// ---------------- edge-balanced wave partition: wstart[w] = first node of wave w ----------------
__global__ void part_k(const int* __restrict__ rowptr, int* __restrict__ wstart,
                       int N, int E, int NW)
{
    int w = blockIdx.x * 256 + threadIdx.x;
    if (w > NW) return;
    if (w == NW) { wstart[NW] = N; return; }
    if (w == 0) { wstart[0] = 0; return; }
    long long target = (long long)E * w / NW;
    int lo = 0, hi = N;                       // first n with rowptr[n] > target
    while (lo < hi) {
        int mid = (lo + hi) >> 1;
        if ((long long)rowptr[mid] <= target) lo = mid + 1; else hi = mid;
    }
    wstart[w] = lo - 1;
}

// ---------------- GEMM: acc = A16[r] @ Wp (fp32 LDS A-tile) ----------------
// A16 rows stride 152 halves; Wp [146][160] fp32. 320 thr: 8 rowgroups x 40 colgroups.
// Epilogue: C32 set: C32 = acc+bias (fp32 h) AND C16 = fp16((acc+bias)*rowscale), stride c16s.
//           C32 null: C16 = fp16(acc), stride c16s, zero-padding cols [146,2*c16s).
__global__ __launch_bounds__(320) void gemm146(
    const __half* __restrict__ A16, const float* __restrict__ Wp,
    __half2* __restrict__ C16, float* __restrict__ C32, int nrows,
    const float* __restrict__ rowscale, const float* __restrict__ bias, int c16s)
{
    __shared__ float As[64 * AS];
    int tid = threadIdx.x;
    int row0 = blockIdx.x * 64;

    {
        const uint4* A4 = reinterpret_cast<const uint4*>(A16);
        for (int i = tid; i < 64 * (AS / 8); i += 320) {
            int r = i / (AS / 8), ch = i % (AS / 8);
            int gr = row0 + r;
            if (gr > nrows - 1) gr = nrows - 1;
            uint4 v = A4[(size_t)gr * (AS / 8) + ch];
            const __half2* hp = reinterpret_cast<const __half2*>(&v);
            float2 t0 = __half22float2(hp[0]);
            float2 t1 = __half22float2(hp[1]);
            float2 t2 = __half22float2(hp[2]);
            float2 t3 = __half22float2(hp[3]);
            float4 f0; f0.x = t0.x; f0.y = t0.y; f0.z = t1.x; f0.w = t1.y;
            float4 f1; f1.x = t2.x; f1.y = t2.y; f1.z = t3.x; f1.w = t3.y;
            *reinterpret_cast<float4*>(&As[r * AS + ch * 8]) = f0;
            *reinterpret_cast<float4*>(&As[r * AS + ch * 8 + 4]) = f1;
        }
    }
    __syncthreads();

    int cg = tid % 40, rg = tid / 40;
    const float4* W4 = reinterpret_cast<const float4*>(Wp);
    float acc[8][4] = {};
    for (int k = 0; k < 144; k += 4) {
        float4 w0 = W4[k * 40 + cg];
        float4 w1 = W4[(k + 1) * 40 + cg];
        float4 w2 = W4[(k + 2) * 40 + cg];
        float4 w3 = W4[(k + 3) * 40 + cg];
#pragma unroll
        for (int i = 0; i < 8; ++i) {
            float4 a = *reinterpret_cast<const float4*>(&As[(rg * 8 + i) * AS + k]);
            acc[i][0] = fmaf(a.x, w0.x, acc[i][0]);
            acc[i][1] = fmaf(a.x, w0.y, acc[i][1]);
            acc[i][2] = fmaf(a.x, w0.z, acc[i][2]);
            acc[i][3] = fmaf(a.x, w0.w, acc[i][3]);
            acc[i][0] = fmaf(a.y, w1.x, acc[i][0]);
            acc[i][1] = fmaf(a.y, w1.y, acc[i][1]);
            acc[i][2] = fmaf(a.y, w1.z, acc[i][2]);
            acc[i][3] = fmaf(a.y, w1.w, acc[i][3]);
            acc[i][0] = fmaf(a.z, w2.x, acc[i][0]);
            acc[i][1] = fmaf(a.z, w2.y, acc[i][1]);
            acc[i][2] = fmaf(a.z, w2.z, acc[i][2]);
            acc[i][3] = fmaf(a.z, w2.w, acc[i][3]);
            acc[i][0] = fmaf(a.w, w3.x, acc[i][0]);
            acc[i][1] = fmaf(a.w, w3.y, acc[i][1]);
            acc[i][2] = fmaf(a.w, w3.z, acc[i][2]);
            acc[i][3] = fmaf(a.w, w3.w, acc[i][3]);
        }
    }
    {   // k = 144,145
        float4 w0 = W4[144 * 40 + cg];
        float4 w1 = W4[145 * 40 + cg];
#pragma unroll
        for (int i = 0; i < 8; ++i) {
            float2 a = *reinterpret_cast<const float2*>(&As[(rg * 8 + i) * AS + 144]);
            acc[i][0] = fmaf(a.x, w0.x, acc[i][0]);
            acc[i][1] = fmaf(a.x, w0.y, acc[i][1]);
            acc[i][2] = fmaf(a.x, w0.z, acc[i][2]);
            acc[i][3] = fmaf(a.x, w0.w, acc[i][3]);
            acc[i][0] = fmaf(a.y, w1.x, acc[i][0]);
            acc[i][1] = fmaf(a.y, w1.y, acc[i][1]);
            acc[i][2] = fmaf(a.y, w1.z, acc[i][2]);
            acc[i][3] = fmaf(a.y, w1.w, acc[i][3]);
        }
    }

    int c = cg * 4;
    bool dopad = (C32 == nullptr);
    __half2 z2h = __floats2half2_rn(0.0f, 0.0f);
    if (c >= D) {
        if (dopad) {       // zero pad cols (j = c/2, c/2+1): covers j 74..79
#pragma unroll
            for (int i = 0; i < 8; ++i) {
                int r = row0 + rg * 8 + i;
                if (r >= nrows) continue;
                C16[(size_t)r * c16s + (c >> 1)] = z2h;
                C16[(size_t)r * c16s + (c >> 1) + 1] = z2h;
            }
        }
        return;
    }
    bool second = (c + 2 < D);
#pragma unroll
    for (int i = 0; i < 8; ++i) {
        int r = row0 + rg * 8 + i;
        if (r >= nrows) continue;
        if (C32) {
            float v0 = acc[i][0] + bias[c], v1 = acc[i][1] + bias[c + 1];
            float2 t; t.x = v0; t.y = v1;
            *reinterpret_cast<float2*>(&C32[(size_t)r * D + c]) = t;
            float s = rowscale[r];
            C16[(size_t)r * c16s + (c >> 1)] = __floats2half2_rn(v0 * s, v1 * s);
            if (second) {
                float v2 = acc[i][2] + bias[c + 2], v3 = acc[i][3] + bias[c + 3];
                float2 t2; t2.x = v2; t2.y = v3;
                *reinterpret_cast<float2*>(&C32[(size_t)r * D + c + 2]) = t2;
                C16[(size_t)r * c16s + (c >> 1) + 1] = __floats2half2_rn(v2 * s, v3 * s);
            }
        } else {
            C16[(size_t)r * c16s + (c >> 1)] = __floats2half2_rn(acc[i][0], acc[i][1]);
            if (second)
                C16[(size_t)r * c16s + (c >> 1) + 1] = __floats2half2_rn(acc[i][2], acc[i][3]);
            else
                C16[(size_t)r * c16s + (c >> 1) + 1] = z2h;   // j=73 pad
        }
    }
}

// ---------------- CSR gather-sum (fp16, 320B rows) + p1 epilogue + BN stats ----------------
// wave w handles nodes [wstart[w], wstart[w+1]) — edge-balanced.
// lane loads half2 {lane, 64+lane(lane<16)}; cols >=146 are zero pads.
__global__ __launch_bounds__(256) void agg_k(
    const __half2* __restrict__ hW2, const int* __restrict__ esrc,
    const int* __restrict__ rowptr, const int* __restrict__ wstart,
    const float* __restrict__ nd, const float* __restrict__ sn,
    const float* __restrict__ bias,
    __half2* __restrict__ hpre2, float* __restrict__ stats, int N)
{
    __shared__ float rs[4][D];
    __shared__ float rq[4][D];
    int lane = threadIdx.x & 63, wave = threadIdx.x >> 6;
    int w = blockIdx.x * 4 + wave;
    int w0 = wstart[w], w1 = wstart[w + 1];

    bool lv = lane < 16;       // load predicate (pads are zero)
    bool v1 = lane < 9;        // store/stats predicate (real cols only)
    int j0 = lane, j1 = 64 + lane;
    int c0 = 2 * lane, c1 = 128 + 2 * lane;
    int c1m = v1 ? c1 : 0;
    float b00 = bias[c0], b01 = bias[c0 + 1];
    float b10 = bias[c1m], b11 = bias[c1m + 1];
    float s00 = 0, s01 = 0, s10 = 0, s11 = 0, q00 = 0, q01 = 0, q10 = 0, q11 = 0;

    for (int n = w0; n < w1; ++n) {
        int e = rowptr[n], ee = rowptr[n + 1];
        float a00 = 0, a01 = 0, a10 = 0, a11 = 0;
        float d00 = 0, d01 = 0, d10 = 0, d11 = 0;
        for (; e + 3 < ee; e += 4) {
            const __half2* r0 = hW2 + (size_t)esrc[e] * HWS;
            const __half2* r1 = hW2 + (size_t)esrc[e + 1] * HWS;
            const __half2* r2 = hW2 + (size_t)esrc[e + 2] * HWS;
            const __half2* r3 = hW2 + (size_t)esrc[e + 3] * HWS;
            float2 f0 = __half22float2(r0[j0]);
            float2 f1 = __half22float2(r1[j0]);
            float2 f2 = __half22float2(r2[j0]);
            float2 f3 = __half22float2(r3[j0]);
            a00 += f0.x + f2.x; a01 += f0.y + f2.y;
            d00 += f1.x + f3.x; d01 += f1.y + f3.y;
            if (lv) {
                float2 g0 = __half22float2(r0[j1]);
                float2 g1 = __half22float2(r1[j1]);
                float2 g2 = __half22float2(r2[j1]);
                float2 g3 = __half22float2(r3[j1]);
                a10 += g0.x + g2.x; a11 += g0.y + g2.y;
                d10 += g1.x + g3.x; d11 += g1.y + g3.y;
            }
        }
        for (; e < ee; ++e) {
            const __half2* ra = hW2 + (size_t)esrc[e] * HWS;
            float2 fa = __half22float2(ra[j0]); a00 += fa.x; a01 += fa.y;
            if (lv) { float2 ga = __half22float2(ra[j1]); a10 += ga.x; a11 += ga.y; }
        }
        a00 += d00; a01 += d01; a10 += d10; a11 += d11;
        float ndv = nd[n], snv = sn[n];
        float h00 = (a00 * ndv + b00) * snv;
        float h01 = (a01 * ndv + b01) * snv;
        hpre2[(size_t)n * (D / 2) + j0] = __floats2half2_rn(h00, h01);
        s00 += h00; q00 = fmaf(h00, h00, q00);
        s01 += h01; q01 = fmaf(h01, h01, q01);
        if (v1) {
            float h10 = (a10 * ndv + b10) * snv;
            float h11 = (a11 * ndv + b11) * snv;
            hpre2[(size_t)n * (D / 2) + j1] = __floats2half2_rn(h10, h11);
            s10 += h10; q10 = fmaf(h10, h10, q10);
            s11 += h11; q11 = fmaf(h11, h11, q11);
        }
    }
    rs[wave][c0] = s00; rs[wave][c0 + 1] = s01;
    rq[wave][c0] = q00; rq[wave][c0 + 1] = q01;
    if (v1) {
        rs[wave][c1] = s10; rs[wave][c1 + 1] = s11;
        rq[wave][c1] = q10; rq[wave][c1 + 1] = q11;
    }
    __syncthreads();
    for (int cc = threadIdx.x; cc < D; cc += 256) {
        atomicAdd(&stats[cc], rs[0][cc] + rs[1][cc] + rs[2][cc] + rs[3][cc]);
        atomicAdd(&stats[D + cc], rq[0][cc] + rq[1][cc] + rq[2][cc] + rq[3][cc]);
    }
}

// ---------------- h += relu(bn(hpre)); hs16 = h*nsrc; hg pooling (bnfin fused) ----------------
__global__ __launch_bounds__(256) void p2hg_k(
    float* __restrict__ h, const __half2* __restrict__ hpre2,
    const float* __restrict__ stats, const float* __restrict__ gamma,
    const float* __restrict__ beta, const float* __restrict__ sn,
    const float* __restrict__ nsrc, const int* __restrict__ gid,
    __half2* __restrict__ hs2, float* __restrict__ hg, int N)
{
    int lane = threadIdx.x & 63, wave = threadIdx.x >> 6;
    int per = (N + gridDim.x - 1) / gridDim.x;
    int n0 = blockIdx.x * per;
    int n1 = min(N, n0 + per);
    int wper = (per + 3) >> 2;
    int w0 = min(n1, n0 + wave * wper);
    int w1 = min(n1, w0 + wper);
    if (w0 >= w1) return;

    bool v1 = lane < 9;
    int j0 = lane, j1 = 64 + lane;
    int c0 = 2 * lane, c1 = 128 + 2 * lane;
    int c1m = v1 ? c1 : 0;
    float inv = 1.0f / (float)N;
    float m00 = stats[c0] * inv,     m01 = stats[c0 + 1] * inv;
    float m10 = stats[c1m] * inv,    m11 = stats[c1m + 1] * inv;
    float v00 = fmaxf(stats[D + c0] * inv - m00 * m00, 0.0f);
    float v01 = fmaxf(stats[D + c0 + 1] * inv - m01 * m01, 0.0f);
    float v10 = fmaxf(stats[D + c1m] * inv - m10 * m10, 0.0f);
    float v11 = fmaxf(stats[D + c1m + 1] * inv - m11 * m11, 0.0f);
    float r00 = rsqrtf(v00 + BN_EPS), r01 = rsqrtf(v01 + BN_EPS);
    float r10 = rsqrtf(v10 + BN_EPS), r11 = rsqrtf(v11 + BN_EPS);
    float g00 = gamma[c0], g01 = gamma[c0 + 1], t00 = beta[c0], t01 = beta[c0 + 1];
    float g10 = gamma[c1m], g11 = gamma[c1m + 1], t10 = beta[c1m], t11 = beta[c1m + 1];

    int g = gid[w0];
    float a00 = 0, a01 = 0, a10 = 0, a11 = 0;
    for (int n = w0; n < w1; ++n) {
        int gr = gid[n];
        if (gr != g) {
            atomicAdd(&hg[(size_t)g * D + c0], a00);
            atomicAdd(&hg[(size_t)g * D + c0 + 1], a01);
            if (v1) {
                atomicAdd(&hg[(size_t)g * D + c1], a10);
                atomicAdd(&hg[(size_t)g * D + c1 + 1], a11);
            }
            a00 = a01 = a10 = a11 = 0;
            g = gr;
        }
        float ns = nsrc[n];
        float w2 = sn[n]; w2 *= w2;
        float2 hv = *reinterpret_cast<float2*>(&h[(size_t)n * D + c0]);
        float2 p0 = __half22float2(hpre2[(size_t)n * (D / 2) + j0]);
        float x0 = hv.x + fmaxf((p0.x - m00) * r00 * g00 + t00, 0.0f);
        float x1 = hv.y + fmaxf((p0.y - m01) * r01 * g01 + t01, 0.0f);
        hv.x = x0; hv.y = x1;
        *reinterpret_cast<float2*>(&h[(size_t)n * D + c0]) = hv;
        hs2[(size_t)n * (AS / 2) + j0] = __floats2half2_rn(x0 * ns, x1 * ns);
        a00 = fmaf(x0, w2, a00);
        a01 = fmaf(x1, w2, a01);
        if (v1) {
            float2 hv1 = *reinterpret_cast<float2*>(&h[(size_t)n * D + c1]);
            float2 p1 = __half22float2(hpre2[(size_t)n * (D / 2) + j1]);
            float x2 = hv1.x + fmaxf((p1.x - m10) * r10 * g10 + t10, 0.0f);
            float x3 = hv1.y + fmaxf((p1.y - m11) * r11 * g11 + t11, 0.0f);
            hv1.x = x2; hv1.y = x3;
            *reinterpret_cast<float2*>(&h[(size_t)n * D + c1]) = hv1;
            hs2[(size_t)n * (AS / 2) + j1] = __floats2half2_rn(x2 * ns, x3 * ns);
            a10 = fmaf(x2, w2, a10);
            a11 = fmaf(x3, w2, a11);
        }
    }
    atomicAdd(&hg[(size_t)g * D + c0], a00);
    atomicAdd(&hg[(size_t)g * D + c0 + 1], a01);
    if (v1) {
        atomicAdd(&hg[(size_t)g * D + c1], a10);
        atomicAdd(&hg[(size_t)g * D + c1 + 1], a11);
    }
}

// ---------------- fused MLP readout: 146 -> 73 -> 36 -> 10 (one block) ----------------
__global__ __launch_bounds__(512) void readout_k(
    const float* __restrict__ hg,
    const float* __restrict__ W0, const float* __restrict__ b0,
    const float* __restrict__ W1, const float* __restrict__ b1,
    const float* __restrict__ W2, const float* __restrict__ b2,
    float* __restrict__ out)
{
    __shared__ float z1[NG * 73];
    __shared__ float z2[NG * 36];
    int t = threadIdx.x;
    for (int idx = t; idx < NG * 73; idx += 512) {
        int m = idx / 73, n = idx % 73;
        float s = b0[n];
        for (int k = 0; k < D; ++k) s = fmaf(hg[m * D + k], W0[k * 73 + n], s);
        z1[idx] = fmaxf(s, 0.0f);
    }
    __syncthreads();
    for (int idx = t; idx < NG * 36; idx += 512) {
        int m = idx / 36, n = idx % 36;
        float s = b1[n];
        for (int k = 0; k < 73; ++k) s = fmaf(z1[m * 73 + k], W1[k * 36 + n], s);
        z2[idx] = fmaxf(s, 0.0f);
    }
    __syncthreads();
    for (int idx = t; idx < NG * 10; idx += 512) {
        int m = idx / 10, n = idx % 10;
        float s = b2[n];
        for (int k = 0; k < 36; ++k) s = fmaf(z2[m * 36 + k], W2[k * 10 + n], s);
        out[idx] = s;
    }
}

extern "C" void kernel_launch(void* const* d_in, const int* in_sizes, int n_in,
                              void* d_out, int out_size, void* d_ws, size_t ws_size,
                              hipStream_t stream)
{
    const float* nodes  = (const float*)d_in[0];
    const float* snorm  = (const float*)d_in[1];
    const float* Wemb   = (const float*)d_in[2];
    const float* bemb   = (const float*)d_in[3];
    const float* Ws     = (const float*)d_in[4];
    const float* bs     = (const float*)d_in[5];
    const float* gammas = (const float*)d_in[6];
    const float* betas  = (const float*)d_in[7];
    const float* Wr0    = (const float*)d_in[8];
    const float* br0    = (const float*)d_in[9];
    const float* Wr1    = (const float*)d_in[10];
    const float* br1    = (const float*)d_in[11];
    const float* Wr2    = (const float*)d_in[12];
    const float* br2    = (const float*)d_in[13];
    const int*   src    = (const int*)d_in[14];
    const int*   dst    = (const int*)d_in[15];
    const int*   gid    = (const int*)d_in[16];

    int N = in_sizes[0] / D;
    int E = in_sizes[14];
    int nb = (N + 255) / 256;
    const int AGB = 2048;          // agg blocks
    const int NW = AGB * 4;        // waves

    float* ws = (float*)d_ws;
    size_t off = 0;
    float* Wp    = ws + off; off += (size_t)5 * D * DP;
    float* nsrc  = ws + off; off += N;
    float* ndst  = ws + off; off += N;
    float* h     = ws + off; off += (size_t)N * D;
    float* stats = ws + off; off += 4 * 4 * D;           // 4 layer slabs
    float* hg    = ws + off; off += (size_t)NG * D;      // contiguous with stats: one memset
    int* cnt_out = (int*)(ws + off); off += N;
    int* cnt_in  = (int*)(ws + off); off += N;
    int* rowptr  = (int*)(ws + off); off += N + 4;
    int* cursor  = (int*)(ws + off); off += N;
    int* esrc    = (int*)(ws + off); off += E;
    int* bsum    = (int*)(ws + off); off += 256;
    int* boff    = (int*)(ws + off); off += 256;
    int* wstart  = (int*)(ws + off); off += NW + 4;
    off = (off + 7) & ~(size_t)7;                        // 16B-align the half region
    __half* hs16    = (__half*)(ws + off); off += (size_t)N * AS / 2;
    __half* nodes16 = (__half*)(ws + off);               // aliases hW16 (disjoint lifetime)
    __half* hW16    = (__half*)(ws + off); off += (size_t)N * (2 * HWS) / 2;
    __half* hpre16  = (__half*)(ws + off); off += (size_t)N * D / 2;

    // setup
    hipMemsetAsync(cnt_out, 0, 2 * (size_t)N * sizeof(int), stream);
    hipMemsetAsync(stats, 0, (16 * D + (size_t)NG * D) * sizeof(float), stream);
    padw_k<<<(5 * D * DP + 255) / 256, 256, 0, stream>>>(Wemb, Ws, Wp);
    cvtnodes_k<<<(N * (AS / 2) + 255) / 256, 256, 0, stream>>>(nodes, (__half2*)nodes16, N);
    deg_k<<<(E + 255) / 256, 256, 0, stream>>>(src, dst, cnt_out, cnt_in, E);
    rsq_k<<<(N + 255) / 256, 256, 0, stream>>>(cnt_out, cnt_in, nsrc, ndst, N);
    pscan1_k<<<nb, 256, 0, stream>>>(cnt_in, bsum, N);
    pscan2_k<<<1, 256, 0, stream>>>(bsum, boff, nb);
    pscan3_k<<<nb, 256, 0, stream>>>(cnt_in, boff, rowptr, cursor, N, E);
    csrfill_k<<<(E + 255) / 256, 256, 0, stream>>>(src, dst, cursor, esrc, E);
    part_k<<<(NW + 256) / 256, 256, 0, stream>>>(rowptr, wstart, N, E, NW);

    int gblk = (N + 63) / 64;
    // embedding: h = nodes@Wemb + b (fp32), hs16 = fp16(h*nsrc) stride 152
    gemm146<<<gblk, 320, 0, stream>>>(nodes16, Wp, (__half2*)hs16, h, N, nsrc, bemb, AS / 2);

    for (int l = 0; l < 4; ++l) {
        float* st = stats + (size_t)l * 4 * D;
        gemm146<<<gblk, 320, 0, stream>>>(hs16, Wp + (size_t)(l + 1) * D * DP,
                                          (__half2*)hW16, nullptr, N, nullptr, nullptr, HWS);
        agg_k<<<AGB, 256, 0, stream>>>((const __half2*)hW16, esrc, rowptr, wstart, ndst, snorm,
                                       bs + (size_t)l * D, (__half2*)hpre16, st, N);
        p2hg_k<<<2048, 256, 0, stream>>>(h, (const __half2*)hpre16, st,
                                         gammas + (size_t)l * D, betas + (size_t)l * D,
                                         snorm, nsrc, gid, (__half2*)hs16, hg, N);
    }

    readout_k<<<1, 512, 0, stream>>>(hg, Wr0, br0, Wr1, br1, Wr2, br2, (float*)d_out);
}

// Round 5
// 842.065 us; speedup vs baseline: 1.2189x; 1.2189x over previous
//
#include <hip/hip_runtime.h>
#include <hip/hip_fp16.h>

#define D 146
#define DP 160      // padded W leading dim in floats (40 float4 per row)
#define AS 152      // padded fp16 activation row (19 uint4 per row)
#define HWS 80      // hW16 gather-payload row stride in half2 (320B, 5 aligned lines)
#define NG 100
#define BN_EPS 1e-5f

// ---------------- pad weights into [5][146][160] fp32 ----------------
__global__ void padw_k(const float* __restrict__ Wemb, const float* __restrict__ Ws,
                       float* __restrict__ Wp)
{
    int idx = blockIdx.x * 256 + threadIdx.x;
    const int per = D * DP;
    if (idx >= 5 * per) return;
    int m = idx / per, rem = idx % per;
    int k = rem / DP, c = rem % DP;
    const float* Wsrc = (m == 0) ? Wemb : (Ws + (size_t)(m - 1) * D * D);
    Wp[idx] = (c < D) ? Wsrc[k * D + c] : 0.0f;
}

// ---------------- nodes fp32 [N][146] -> fp16 [N][152] ----------------
__global__ void cvtnodes_k(const float* __restrict__ nodes, __half2* __restrict__ out2, int N)
{
    int idx = blockIdx.x * 256 + threadIdx.x;
    if (idx >= N * (AS / 2)) return;
    int r = idx / (AS / 2), j = idx % (AS / 2);
    int c = 2 * j;
    float v0 = (c < D) ? nodes[(size_t)r * D + c] : 0.0f;
    float v1 = (c + 1 < D) ? nodes[(size_t)r * D + c + 1] : 0.0f;
    out2[idx] = __floats2half2_rn(v0, v1);
}

// ---------------- degree histograms ----------------
__global__ void deg_k(const int* __restrict__ src, const int* __restrict__ dst,
                      int* __restrict__ co, int* __restrict__ ci, int E)
{
    int e = blockIdx.x * 256 + threadIdx.x;
    if (e >= E) return;
    atomicAdd(&co[src[e]], 1);
    atomicAdd(&ci[dst[e]], 1);
}

__global__ void rsq_k(const int* __restrict__ co, const int* __restrict__ ci,
                      float* __restrict__ ns, float* __restrict__ nd, int N)
{
    int i = blockIdx.x * 256 + threadIdx.x;
    if (i >= N) return;
    ns[i] = rsqrtf(fmaxf((float)co[i], 1.0f));
    nd[i] = rsqrtf(fmaxf((float)ci[i], 1.0f));
}

// ---------------- parallel exclusive scan (3 phases) ----------------
__global__ __launch_bounds__(256) void pscan1_k(const int* __restrict__ cnt,
                                                int* __restrict__ bsum, int N)
{
    __shared__ int lds[256];
    int t = blockIdx.x * 256 + threadIdx.x;
    lds[threadIdx.x] = (t < N) ? cnt[t] : 0;
    __syncthreads();
    for (int s = 128; s > 0; s >>= 1) {
        if (threadIdx.x < s) lds[threadIdx.x] += lds[threadIdx.x + s];
        __syncthreads();
    }
    if (threadIdx.x == 0) bsum[blockIdx.x] = lds[0];
}

__global__ __launch_bounds__(256) void pscan2_k(const int* __restrict__ bsum,
                                                int* __restrict__ boff, int nb)
{
    __shared__ int lds[256];
    int t = threadIdx.x;
    int v = (t < nb) ? bsum[t] : 0;
    lds[t] = v;
    __syncthreads();
    for (int off = 1; off < 256; off <<= 1) {
        int u = (t >= off) ? lds[t - off] : 0;
        __syncthreads();
        lds[t] += u;
        __syncthreads();
    }
    boff[t] = lds[t] - v;
}

__global__ __launch_bounds__(256) void pscan3_k(const int* __restrict__ cnt,
                                                const int* __restrict__ boff,
                                                int* __restrict__ rowptr,
                                                int* __restrict__ cursor, int N, int E)
{
    __shared__ int lds[256];
    int t = blockIdx.x * 256 + threadIdx.x;
    int v = (t < N) ? cnt[t] : 0;
    lds[threadIdx.x] = v;
    __syncthreads();
    for (int off = 1; off < 256; off <<= 1) {
        int u = (threadIdx.x >= off) ? lds[threadIdx.x - off] : 0;
        __syncthreads();
        lds[threadIdx.x] += u;
        __syncthreads();
    }
    if (t < N) {
        int r = boff[blockIdx.x] + lds[threadIdx.x] - v;
        rowptr[t] = r;
        cursor[t] = r;
    }
    if (t == 0) rowptr[N] = E;
}

// ---------------- CSR fill ----------------
__global__ void csrfill_k(const int* __restrict__ src, const int* __restrict__ dst,
                          int* __restrict__ cursor, int* __restrict__ esrc, int E)
{
    int e = blockIdx.x * 256 + threadIdx.x;
    if (e >= E) return;
    int pos = atomicAdd(&cursor[dst[e]], 1);
    esrc[pos] = src[e];
}

// ---------------- edge-balanced wave partition: wstart[w] = first node of wave w ----------------
__global__ void part_k(const int* __restrict__ rowptr, int* __restrict__ wstart,
                       int N, int E, int NW)
{
    int w = blockIdx.x * 256 + threadIdx.x;
    if (w > NW) return;
    if (w == NW) { wstart[NW] = N; return; }
    if (w == 0) { wstart[0] = 0; return; }
    long long target = (long long)E * w / NW;
    int lo = 0, hi = N;                       // first n with rowptr[n] > target
    while (lo < hi) {
        int mid = (lo + hi) >> 1;
        if ((long long)rowptr[mid] <= target) lo = mid + 1; else hi = mid;
    }
    wstart[w] = lo - 1;
}

// ---------------- GEMM: acc = A16[r] @ Wp (fp32 LDS A-tile) ----------------
__global__ __launch_bounds__(320) void gemm146(
    const __half* __restrict__ A16, const float* __restrict__ Wp,
    __half2* __restrict__ C16, float* __restrict__ C32, int nrows,
    const float* __restrict__ rowscale, const float* __restrict__ bias, int c16s)
{
    __shared__ float As[64 * AS];
    int tid = threadIdx.x;
    int row0 = blockIdx.x * 64;

    {
        const uint4* A4 = reinterpret_cast<const uint4*>(A16);
        for (int i = tid; i < 64 * (AS / 8); i += 320) {
            int r = i / (AS / 8), ch = i % (AS / 8);
            int gr = row0 + r;
            if (gr > nrows - 1) gr = nrows - 1;
            uint4 v = A4[(size_t)gr * (AS / 8) + ch];
            const __half2* hp = reinterpret_cast<const __half2*>(&v);
            float2 t0 = __half22float2(hp[0]);
            float2 t1 = __half22float2(hp[1]);
            float2 t2 = __half22float2(hp[2]);
            float2 t3 = __half22float2(hp[3]);
            float4 f0; f0.x = t0.x; f0.y = t0.y; f0.z = t1.x; f0.w = t1.y;
            float4 f1; f1.x = t2.x; f1.y = t2.y; f1.z = t3.x; f1.w = t3.y;
            *reinterpret_cast<float4*>(&As[r * AS + ch * 8]) = f0;
            *reinterpret_cast<float4*>(&As[r * AS + ch * 8 + 4]) = f1;
        }
    }
    __syncthreads();

    int cg = tid % 40, rg = tid / 40;
    const float4* W4 = reinterpret_cast<const float4*>(Wp);
    float acc[8][4] = {};
    for (int k = 0; k < 144; k += 4) {
        float4 w0 = W4[k * 40 + cg];
        float4 w1 = W4[(k + 1) * 40 + cg];
        float4 w2 = W4[(k + 2) * 40 + cg];
        float4 w3 = W4[(k + 3) * 40 + cg];
#pragma unroll
        for (int i = 0; i < 8; ++i) {
            float4 a = *reinterpret_cast<const float4*>(&As[(rg * 8 + i) * AS + k]);
            acc[i][0] = fmaf(a.x, w0.x, acc[i][0]);
            acc[i][1] = fmaf(a.x, w0.y, acc[i][1]);
            acc[i][2] = fmaf(a.x, w0.z, acc[i][2]);
            acc[i][3] = fmaf(a.x, w0.w, acc[i][3]);
            acc[i][0] = fmaf(a.y, w1.x, acc[i][0]);
            acc[i][1] = fmaf(a.y, w1.y, acc[i][1]);
            acc[i][2] = fmaf(a.y, w1.z, acc[i][2]);
            acc[i][3] = fmaf(a.y, w1.w, acc[i][3]);
            acc[i][0] = fmaf(a.z, w2.x, acc[i][0]);
            acc[i][1] = fmaf(a.z, w2.y, acc[i][1]);
            acc[i][2] = fmaf(a.z, w2.z, acc[i][2]);
            acc[i][3] = fmaf(a.z, w2.w, acc[i][3]);
            acc[i][0] = fmaf(a.w, w3.x, acc[i][0]);
            acc[i][1] = fmaf(a.w, w3.y, acc[i][1]);
            acc[i][2] = fmaf(a.w, w3.z, acc[i][2]);
            acc[i][3] = fmaf(a.w, w3.w, acc[i][3]);
        }
    }
    {   // k = 144,145
        float4 w0 = W4[144 * 40 + cg];
        float4 w1 = W4[145 * 40 + cg];
#pragma unroll
        for (int i = 0; i < 8; ++i) {
            float2 a = *reinterpret_cast<const float2*>(&As[(rg * 8 + i) * AS + 144]);
            acc[i][0] = fmaf(a.x, w0.x, acc[i][0]);
            acc[i][1] = fmaf(a.x, w0.y, acc[i][1]);
            acc[i][2] = fmaf(a.x, w0.z, acc[i][2]);
            acc[i][3] = fmaf(a.x, w0.w, acc[i][3]);
            acc[i][0] = fmaf(a.y, w1.x, acc[i][0]);
            acc[i][1] = fmaf(a.y, w1.y, acc[i][1]);
            acc[i][2] = fmaf(a.y, w1.z, acc[i][2]);
            acc[i][3] = fmaf(a.y, w1.w, acc[i][3]);
        }
    }

    int c = cg * 4;
    bool dopad = (C32 == nullptr);
    __half2 z2h = __floats2half2_rn(0.0f, 0.0f);
    if (c >= D) {
        if (dopad) {
#pragma unroll
            for (int i = 0; i < 8; ++i) {
                int r = row0 + rg * 8 + i;
                if (r >= nrows) continue;
                C16[(size_t)r * c16s + (c >> 1)] = z2h;
                C16[(size_t)r * c16s + (c >> 1) + 1] = z2h;
            }
        }
        return;
    }
    bool second = (c + 2 < D);
#pragma unroll
    for (int i = 0; i < 8; ++i) {
        int r = row0 + rg * 8 + i;
        if (r >= nrows) continue;
        if (C32) {
            float v0 = acc[i][0] + bias[c], v1 = acc[i][1] + bias[c + 1];
            float2 t; t.x = v0; t.y = v1;
            *reinterpret_cast<float2*>(&C32[(size_t)r * D + c]) = t;
            float s = rowscale[r];
            C16[(size_t)r * c16s + (c >> 1)] = __floats2half2_rn(v0 * s, v1 * s);
            if (second) {
                float v2 = acc[i][2] + bias[c + 2], v3 = acc[i][3] + bias[c + 3];
                float2 t2; t2.x = v2; t2.y = v3;
                *reinterpret_cast<float2*>(&C32[(size_t)r * D + c + 2]) = t2;
                C16[(size_t)r * c16s + (c >> 1) + 1] = __floats2half2_rn(v2 * s, v3 * s);
            }
        } else {
            C16[(size_t)r * c16s + (c >> 1)] = __floats2half2_rn(acc[i][0], acc[i][1]);
            if (second)
                C16[(size_t)r * c16s + (c >> 1) + 1] = __floats2half2_rn(acc[i][2], acc[i][3]);
            else
                C16[(size_t)r * c16s + (c >> 1) + 1] = z2h;   // j=73 pad
        }
    }
}

// ---------------- CSR gather-sum (fp16, 320B rows) + p1 epilogue + BN stats ----------------
__global__ __launch_bounds__(256) void agg_k(
    const __half2* __restrict__ hW2, const int* __restrict__ esrc,
    const int* __restrict__ rowptr, const int* __restrict__ wstart,
    const float* __restrict__ nd, const float* __restrict__ sn,
    const float* __restrict__ bias,
    __half2* __restrict__ hpre2, float* __restrict__ stats, int N)
{
    __shared__ float rs[4][D];
    __shared__ float rq[4][D];
    int lane = threadIdx.x & 63, wave = threadIdx.x >> 6;
    int w = blockIdx.x * 4 + wave;
    int w0 = wstart[w], w1 = wstart[w + 1];

    bool lv = lane < 16;       // load predicate (pads are zero)
    bool v1 = lane < 9;        // store/stats predicate
    int j0 = lane, j1 = 64 + lane;
    int c0 = 2 * lane, c1 = 128 + 2 * lane;
    int c1m = v1 ? c1 : 0;
    float b00 = bias[c0], b01 = bias[c0 + 1];
    float b10 = bias[c1m], b11 = bias[c1m + 1];
    float s00 = 0, s01 = 0, s10 = 0, s11 = 0, q00 = 0, q01 = 0, q10 = 0, q11 = 0;

    for (int n = w0; n < w1; ++n) {
        int e = rowptr[n], ee = rowptr[n + 1];
        float a00 = 0, a01 = 0, a10 = 0, a11 = 0;
        float d00 = 0, d01 = 0, d10 = 0, d11 = 0;
        for (; e + 3 < ee; e += 4) {
            const __half2* r0 = hW2 + (size_t)esrc[e] * HWS;
            const __half2* r1 = hW2 + (size_t)esrc[e + 1] * HWS;
            const __half2* r2 = hW2 + (size_t)esrc[e + 2] * HWS;
            const __half2* r3 = hW2 + (size_t)esrc[e + 3] * HWS;
            float2 f0 = __half22float2(r0[j0]);
            float2 f1 = __half22float2(r1[j0]);
            float2 f2 = __half22float2(r2[j0]);
            float2 f3 = __half22float2(r3[j0]);
            a00 += f0.x + f2.x; a01 += f0.y + f2.y;
            d00 += f1.x + f3.x; d01 += f1.y + f3.y;
            if (lv) {
                float2 g0 = __half22float2(r0[j1]);
                float2 g1 = __half22float2(r1[j1]);
                float2 g2 = __half22float2(r2[j1]);
                float2 g3 = __half22float2(r3[j1]);
                a10 += g0.x + g2.x; a11 += g0.y + g2.y;
                d10 += g1.x + g3.x; d11 += g1.y + g3.y;
            }
        }
        for (; e < ee; ++e) {
            const __half2* ra = hW2 + (size_t)esrc[e] * HWS;
            float2 fa = __half22float2(ra[j0]); a00 += fa.x; a01 += fa.y;
            if (lv) { float2 ga = __half22float2(ra[j1]); a10 += ga.x; a11 += ga.y; }
        }
        a00 += d00; a01 += d01; a10 += d10; a11 += d11;
        float ndv = nd[n], snv = sn[n];
        float h00 = (a00 * ndv + b00) * snv;
        float h01 = (a01 * ndv + b01) * snv;
        hpre2[(size_t)n * (D / 2) + j0] = __floats2half2_rn(h00, h01);
        s00 += h00; q00 = fmaf(h00, h00, q00);
        s01 += h01; q01 = fmaf(h01, h01, q01);
        if (v1) {
            float h10 = (a10 * ndv + b10) * snv;
            float h11 = (a11 * ndv + b11) * snv;
            hpre2[(size_t)n * (D / 2) + j1] = __floats2half2_rn(h10, h11);
            s10 += h10; q10 = fmaf(h10, h10, q10);
            s11 += h11; q11 = fmaf(h11, h11, q11);
        }
    }
    rs[wave][c0] = s00; rs[wave][c0 + 1] = s01;
    rq[wave][c0] = q00; rq[wave][c0 + 1] = q01;
    if (v1) {
        rs[wave][c1] = s10; rs[wave][c1 + 1] = s11;
        rq[wave][c1] = q10; rq[wave][c1 + 1] = q11;
    }
    __syncthreads();
    for (int cc = threadIdx.x; cc < D; cc += 256) {
        atomicAdd(&stats[cc], rs[0][cc] + rs[1][cc] + rs[2][cc] + rs[3][cc]);
        atomicAdd(&stats[D + cc], rq[0][cc] + rq[1][cc] + rq[2][cc] + rq[3][cc]);
    }
}

// ---------------- h += relu(bn(hpre)); hs16 = h*nsrc; hg pooling (bnfin fused) ----------------
// hs2 == nullptr => last layer: skip h and hs16 stores (dead after pooling).
__global__ __launch_bounds__(256) void p2hg_k(
    float* __restrict__ h, const __half2* __restrict__ hpre2,
    const float* __restrict__ stats, const float* __restrict__ gamma,
    const float* __restrict__ beta, const float* __restrict__ sn,
    const float* __restrict__ nsrc, const int* __restrict__ gid,
    __half2* __restrict__ hs2, float* __restrict__ hg, int N)
{
    int lane = threadIdx.x & 63, wave = threadIdx.x >> 6;
    int per = (N + gridDim.x - 1) / gridDim.x;
    int n0 = blockIdx.x * per;
    int n1 = min(N, n0 + per);
    int wper = (per + 3) >> 2;
    int w0 = min(n1, n0 + wave * wper);
    int w1 = min(n1, w0 + wper);
    if (w0 >= w1) return;

    bool v1 = lane < 9;
    bool wr = (hs2 != nullptr);
    int j0 = lane, j1 = 64 + lane;
    int c0 = 2 * lane, c1 = 128 + 2 * lane;
    int c1m = v1 ? c1 : 0;
    float inv = 1.0f / (float)N;
    float m00 = stats[c0] * inv,     m01 = stats[c0 + 1] * inv;
    float m10 = stats[c1m] * inv,    m11 = stats[c1m + 1] * inv;
    float v00 = fmaxf(stats[D + c0] * inv - m00 * m00, 0.0f);
    float v01 = fmaxf(stats[D + c0 + 1] * inv - m01 * m01, 0.0f);
    float v10 = fmaxf(stats[D + c1m] * inv - m10 * m10, 0.0f);
    float v11 = fmaxf(stats[D + c1m + 1] * inv - m11 * m11, 0.0f);
    float r00 = rsqrtf(v00 + BN_EPS), r01 = rsqrtf(v01 + BN_EPS);
    float r10 = rsqrtf(v10 + BN_EPS), r11 = rsqrtf(v11 + BN_EPS);
    float g00 = gamma[c0], g01 = gamma[c0 + 1], t00 = beta[c0], t01 = beta[c0 + 1];
    float g10 = gamma[c1m], g11 = gamma[c1m + 1], t10 = beta[c1m], t11 = beta[c1m + 1];

    int g = gid[w0];
    float a00 = 0, a01 = 0, a10 = 0, a11 = 0;
    for (int n = w0; n < w1; ++n) {
        int gr = gid[n];
        if (gr != g) {
            atomicAdd(&hg[(size_t)g * D + c0], a00);
            atomicAdd(&hg[(size_t)g * D + c0 + 1], a01);
            if (v1) {
                atomicAdd(&hg[(size_t)g * D + c1], a10);
                atomicAdd(&hg[(size_t)g * D + c1 + 1], a11);
            }
            a00 = a01 = a10 = a11 = 0;
            g = gr;
        }
        float ns = nsrc[n];
        float w2 = sn[n]; w2 *= w2;
        float2 hv = *reinterpret_cast<float2*>(&h[(size_t)n * D + c0]);
        float2 p0 = __half22float2(hpre2[(size_t)n * (D / 2) + j0]);
        float x0 = hv.x + fmaxf((p0.x - m00) * r00 * g00 + t00, 0.0f);
        float x1 = hv.y + fmaxf((p0.y - m01) * r01 * g01 + t01, 0.0f);
        if (wr) {
            hv.x = x0; hv.y = x1;
            *reinterpret_cast<float2*>(&h[(size_t)n * D + c0]) = hv;
            hs2[(size_t)n * (AS / 2) + j0] = __floats2half2_rn(x0 * ns, x1 * ns);
        }
        a00 = fmaf(x0, w2, a00);
        a01 = fmaf(x1, w2, a01);
        if (v1) {
            float2 hv1 = *reinterpret_cast<float2*>(&h[(size_t)n * D + c1]);
            float2 p1 = __half22float2(hpre2[(size_t)n * (D / 2) + j1]);
            float x2 = hv1.x + fmaxf((p1.x - m10) * r10 * g10 + t10, 0.0f);
            float x3 = hv1.y + fmaxf((p1.y - m11) * r11 * g11 + t11, 0.0f);
            if (wr) {
                hv1.x = x2; hv1.y = x3;
                *reinterpret_cast<float2*>(&h[(size_t)n * D + c1]) = hv1;
                hs2[(size_t)n * (AS / 2) + j1] = __floats2half2_rn(x2 * ns, x3 * ns);
            }
            a10 = fmaf(x2, w2, a10);
            a11 = fmaf(x3, w2, a11);
        }
    }
    atomicAdd(&hg[(size_t)g * D + c0], a00);
    atomicAdd(&hg[(size_t)g * D + c0 + 1], a01);
    if (v1) {
        atomicAdd(&hg[(size_t)g * D + c1], a10);
        atomicAdd(&hg[(size_t)g * D + c1 + 1], a11);
    }
}

// ---------------- fused MLP readout: one block per graph ----------------
__global__ __launch_bounds__(128) void readout_k(
    const float* __restrict__ hg,
    const float* __restrict__ W0, const float* __restrict__ b0,
    const float* __restrict__ W1, const float* __restrict__ b1,
    const float* __restrict__ W2, const float* __restrict__ b2,
    float* __restrict__ out)
{
    __shared__ float hl[D];
    __shared__ float z1[73];
    __shared__ float z2[36];
    int g = blockIdx.x;
    int t = threadIdx.x;
    for (int i = t; i < D; i += 128) hl[i] = hg[(size_t)g * D + i];
    __syncthreads();
    if (t < 73) {
        float s = b0[t];
        for (int k = 0; k < D; ++k) s = fmaf(hl[k], W0[k * 73 + t], s);
        z1[t] = fmaxf(s, 0.0f);
    }
    __syncthreads();
    if (t < 36) {
        float s = b1[t];
        for (int k = 0; k < 73; ++k) s = fmaf(z1[k], W1[k * 36 + t], s);
        z2[t] = fmaxf(s, 0.0f);
    }
    __syncthreads();
    if (t < 10) {
        float s = b2[t];
        for (int k = 0; k < 36; ++k) s = fmaf(z2[k], W2[k * 10 + t], s);
        out[g * 10 + t] = s;
    }
}

extern "C" void kernel_launch(void* const* d_in, const int* in_sizes, int n_in,
                              void* d_out, int out_size, void* d_ws, size_t ws_size,
                              hipStream_t stream)
{
    const float* nodes  = (const float*)d_in[0];
    const float* snorm  = (const float*)d_in[1];
    const float* Wemb   = (const float*)d_in[2];
    const float* bemb   = (const float*)d_in[3];
    const float* Ws     = (const float*)d_in[4];
    const float* bs     = (const float*)d_in[5];
    const float* gammas = (const float*)d_in[6];
    const float* betas  = (const float*)d_in[7];
    const float* Wr0    = (const float*)d_in[8];
    const float* br0    = (const float*)d_in[9];
    const float* Wr1    = (const float*)d_in[10];
    const float* br1    = (const float*)d_in[11];
    const float* Wr2    = (const float*)d_in[12];
    const float* br2    = (const float*)d_in[13];
    const int*   src    = (const int*)d_in[14];
    const int*   dst    = (const int*)d_in[15];
    const int*   gid    = (const int*)d_in[16];

    int N = in_sizes[0] / D;
    int E = in_sizes[14];
    int nb = (N + 255) / 256;
    const int AGB = 2048;          // agg blocks
    const int NW = AGB * 4;        // waves

    float* ws = (float*)d_ws;
    size_t off = 0;
    float* Wp    = ws + off; off += (size_t)5 * D * DP;
    float* nsrc  = ws + off; off += N;
    float* ndst  = ws + off; off += N;
    float* h     = ws + off; off += (size_t)N * D;
    float* stats = ws + off; off += 4 * 4 * D;           // 4 layer slabs
    float* hg    = ws + off; off += (size_t)NG * D;      // contiguous with stats: one memset
    int* cnt_out = (int*)(ws + off); off += N;
    int* cnt_in  = (int*)(ws + off); off += N;
    int* rowptr  = (int*)(ws + off); off += N + 4;
    int* cursor  = (int*)(ws + off); off += N;
    int* esrc    = (int*)(ws + off); off += E;
    int* bsum    = (int*)(ws + off); off += 256;
    int* boff    = (int*)(ws + off); off += 256;
    int* wstart  = (int*)(ws + off); off += NW + 4;
    off = (off + 7) & ~(size_t)7;                        // 16B-align the half region
    __half* hs16    = (__half*)(ws + off); off += (size_t)N * AS / 2;
    __half* nodes16 = (__half*)(ws + off);               // aliases hW16 (disjoint lifetime)
    __half* hW16    = (__half*)(ws + off); off += (size_t)N * (2 * HWS) / 2;
    __half* hpre16  = (__half*)(ws + off); off += (size_t)N * D / 2;

    // setup
    hipMemsetAsync(cnt_out, 0, 2 * (size_t)N * sizeof(int), stream);
    hipMemsetAsync(stats, 0, (16 * D + (size_t)NG * D) * sizeof(float), stream);
    padw_k<<<(5 * D * DP + 255) / 256, 256, 0, stream>>>(Wemb, Ws, Wp);
    cvtnodes_k<<<(N * (AS / 2) + 255) / 256, 256, 0, stream>>>(nodes, (__half2*)nodes16, N);
    deg_k<<<(E + 255) / 256, 256, 0, stream>>>(src, dst, cnt_out, cnt_in, E);
    rsq_k<<<(N + 255) / 256, 256, 0, stream>>>(cnt_out, cnt_in, nsrc, ndst, N);
    pscan1_k<<<nb, 256, 0, stream>>>(cnt_in, bsum, N);
    pscan2_k<<<1, 256, 0, stream>>>(bsum, boff, nb);
    pscan3_k<<<nb, 256, 0, stream>>>(cnt_in, boff, rowptr, cursor, N, E);
    csrfill_k<<<(E + 255) / 256, 256, 0, stream>>>(src, dst, cursor, esrc, E);
    part_k<<<(NW + 256) / 256, 256, 0, stream>>>(rowptr, wstart, N, E, NW);

    int gblk = (N + 63) / 64;
    // embedding: h = nodes@Wemb + b (fp32), hs16 = fp16(h*nsrc) stride 152
    gemm146<<<gblk, 320, 0, stream>>>(nodes16, Wp, (__half2*)hs16, h, N, nsrc, bemb, AS / 2);

    for (int l = 0; l < 4; ++l) {
        float* st = stats + (size_t)l * 4 * D;
        gemm146<<<gblk, 320, 0, stream>>>(hs16, Wp + (size_t)(l + 1) * D * DP,
                                          (__half2*)hW16, nullptr, N, nullptr, nullptr, HWS);
        agg_k<<<AGB, 256, 0, stream>>>((const __half2*)hW16, esrc, rowptr, wstart, ndst, snorm,
                                       bs + (size_t)l * D, (__half2*)hpre16, st, N);
        p2hg_k<<<2048, 256, 0, stream>>>(h, (const __half2*)hpre16, st,
                                         gammas + (size_t)l * D, betas + (size_t)l * D,
                                         snorm, nsrc, gid,
                                         (l == 3) ? nullptr : (__half2*)hs16, hg, N);
    }

    readout_k<<<NG, 128, 0, stream>>>(hg, Wr0, br0, Wr1, br1, Wr2, br2, (float*)d_out);
}